// Round 3
// baseline (18.572 us; speedup 1.0000x reference)
//
#include <hip/hip_runtime.h>

// Problem constants (fixed by the reference)
#define NROWS   12288   // NUM_INPUT_ROWS
#define NCOLS   256     // CODEBOOK_DIM
#define HID     512     // HIDDEN_DIM
#define NNODES  16384   // NUM_NODES (zero-padded rows contribute nothing to the sum)

// ---------------------------------------------------------------------------
// K1: partial column sums of x. x is [NROWS][NCOLS] f32 row-major = 64 float4
// per row. 256 blocks x 256 threads (one block/CU): thread t owns float4-col
// (t&63), row offset (t>>6). 12 grid-stride iterations -> 12 independent
// 16B loads in flight per thread. Each block writes a 256-float partial
// colsum to wsA[bid*256 ..].
// ---------------------------------------------------------------------------
__global__ __launch_bounds__(256) void colsum_partial(const float* __restrict__ x,
                                                      float* __restrict__ wsA,
                                                      int nblocks) {
    const int t    = threadIdx.x;
    const int c4   = t & 63;
    const int rofs = t >> 6;
    const int bid  = blockIdx.x;
    const float4* __restrict__ x4 = (const float4*)x;

    float4 acc = make_float4(0.f, 0.f, 0.f, 0.f);
    for (int r = bid * 4 + rofs; r < NROWS; r += 4 * nblocks) {
        float4 v = x4[r * 64 + c4];
        acc.x += v.x; acc.y += v.y; acc.z += v.z; acc.w += v.w;
    }

    __shared__ float4 s[256];
    s[t] = acc;
    __syncthreads();
    if (t < 64) {
        float4 a = s[t], b = s[t + 64], c = s[t + 128], d = s[t + 192];
        float4 r;
        r.x = a.x + b.x + c.x + d.x;
        r.y = a.y + b.y + c.y + d.y;
        r.z = a.z + b.z + c.z + d.z;
        r.w = a.w + b.w + c.w + d.w;
        ((float4*)wsA)[bid * 64 + t] = r;
    }
}

// ---------------------------------------------------------------------------
// K2 (fused tail): 16 blocks x 512 threads. Each block REDUNDANTLY computes
// the full scalar s, then broadcasts it to its 1/16 slice of out.
//   Phase A: reduce nb partial colsums -> colmean[256] in LDS.
//            512 threads = 64 float4-cols x 8 groups; nb/8 float4 loads each.
//   Phase B: thread t computes h[t] = relu(b1[t] + sum_c colmean[c]*W1[c][t])
//            with 4 split accumulators (breaks the 256-long FMA dep chain).
//            W1 reads fully coalesced (512 consecutive floats per c).
//   Phase C: s = relu(dot(h, W2) + b2) via shuffle + LDS block reduce.
//   Phase D: block bid writes out[bid*1024 .. +1024) as 256 float4 stores.
// W1 redundancy = 16 x 512 KB = 8 MB of L2 traffic (~0.3 us) -- cheaper than
// another kernel launch + inter-kernel drain.
// ---------------------------------------------------------------------------
__global__ __launch_bounds__(512) void fused_tail(const float* __restrict__ wsA,
                                                  const float* __restrict__ W1,
                                                  const float* __restrict__ b1,
                                                  const float* __restrict__ W2,
                                                  const float* __restrict__ b2,
                                                  float* __restrict__ out,
                                                  int nb) {
    __shared__ float4 tmp4[512];
    __shared__ float  colmean[NCOLS];
    __shared__ float  warpsums[8];
    __shared__ float  s_scalar;

    const int t = threadIdx.x;

    // ---- Phase A: colmean ----
    {
        const int c4  = t & 63;
        const int grp = t >> 6;              // 0..7
        const int per = nb >> 3;             // partials per group
        const float4* __restrict__ wsA4 = (const float4*)wsA;

        float4 acc = make_float4(0.f, 0.f, 0.f, 0.f);
        const int k0 = grp * per;
        #pragma unroll 4
        for (int k = k0; k < k0 + per; ++k) {
            float4 v = wsA4[k * 64 + c4];
            acc.x += v.x; acc.y += v.y; acc.z += v.z; acc.w += v.w;
        }
        tmp4[t] = acc;
        __syncthreads();
        if (t < 64) {
            float4 a = tmp4[t];
            #pragma unroll
            for (int g = 1; g < 8; ++g) {
                float4 v = tmp4[g * 64 + t];
                a.x += v.x; a.y += v.y; a.z += v.z; a.w += v.w;
            }
            const float inv = 1.0f / (float)NNODES;
            a.x *= inv; a.y *= inv; a.z *= inv; a.w *= inv;
            ((float4*)colmean)[t] = a;
        }
        __syncthreads();
    }

    // ---- Phase B: h[t] with 4 split accumulators ----
    float a0 = 0.f, a1 = 0.f, a2 = 0.f, a3 = 0.f;
    #pragma unroll 4
    for (int c = 0; c < NCOLS; c += 4) {
        a0 = fmaf(colmean[c + 0], W1[(c + 0) * HID + t], a0);
        a1 = fmaf(colmean[c + 1], W1[(c + 1) * HID + t], a1);
        a2 = fmaf(colmean[c + 2], W1[(c + 2) * HID + t], a2);
        a3 = fmaf(colmean[c + 3], W1[(c + 3) * HID + t], a3);
    }
    const float h = fmaxf(b1[t] + ((a0 + a1) + (a2 + a3)), 0.0f);

    // ---- Phase C: s = relu(dot(h, W2) + b2) ----
    float p = h * W2[t];
    #pragma unroll
    for (int off = 32; off > 0; off >>= 1)
        p += __shfl_down(p, off, 64);
    if ((t & 63) == 0) warpsums[t >> 6] = p;
    __syncthreads();
    if (t == 0) {
        float s = b2[0];
        #pragma unroll
        for (int w = 0; w < 8; ++w) s += warpsums[w];
        s_scalar = fmaxf(s, 0.0f);
    }
    __syncthreads();

    // ---- Phase D: broadcast slice ----
    const float v = s_scalar;
    if (t < 256) {
        float4 f4 = make_float4(v, v, v, v);
        ((float4*)out)[blockIdx.x * 256 + t] = f4;
    }
}

extern "C" void kernel_launch(void* const* d_in, const int* in_sizes, int n_in,
                              void* d_out, int out_size, void* d_ws, size_t ws_size,
                              hipStream_t stream) {
    const float* x  = (const float*)d_in[0];
    const float* W1 = (const float*)d_in[1];
    const float* b1 = (const float*)d_in[2];
    const float* W2 = (const float*)d_in[3];
    const float* b2 = (const float*)d_in[4];
    float* out = (float*)d_out;
    float* wsA = (float*)d_ws;

    // nb partial-colsum blocks (multiple of 8 for K2's 8-way split).
    int nb = 256;
    {
        size_t need = (size_t)nb * NCOLS * sizeof(float);
        if (ws_size < need) {
            nb = (int)(ws_size / (NCOLS * sizeof(float)));
            nb &= ~7;                 // multiple of 8
            if (nb < 8) nb = 8;       // ws pathologically small; still correct
        }
    }

    colsum_partial<<<nb, 256, 0, stream>>>(x, wsA, nb);
    fused_tail<<<16, 512, 0, stream>>>(wsA, W1, b1, W2, b2, out, nb);
}

// Round 4
// 17.858 us; speedup vs baseline: 1.0400x; 1.0400x over previous
//
#include <hip/hip_runtime.h>

// Problem constants (fixed by the reference)
#define NROWS   12288   // NUM_INPUT_ROWS
#define NCOLS   256     // CODEBOOK_DIM
#define HID     512     // HIDDEN_DIM
#define NNODES  16384   // NUM_NODES (zero-padded rows contribute nothing to the sum)
#define TB      8       // tail blocks (co-resident: 8 << 256 CUs)

// ws layout (floats): [0, nb*256) partial colsums | [nb*256, +8) partial s | +8: counter(uint)

// ---------------------------------------------------------------------------
// K1: partial column sums of x. x is [NROWS][NCOLS] f32 row-major = 64 float4
// per row. nb blocks x 256 threads: thread t owns float4-col (t&63), row
// offset (t>>6). Each block writes a 256-float partial colsum.
// Block 0 also zeroes the tail sync counter (race-free: tail kernel starts
// only after this kernel completes; kernel boundary is a device-scope release).
// ---------------------------------------------------------------------------
__global__ __launch_bounds__(256) void colsum_partial(const float* __restrict__ x,
                                                      float* __restrict__ wsA,
                                                      unsigned int* __restrict__ cnt,
                                                      int nblocks) {
    const int t    = threadIdx.x;
    const int c4   = t & 63;
    const int rofs = t >> 6;
    const int bid  = blockIdx.x;

    if (bid == 0 && t == 0) *cnt = 0u;

    const float4* __restrict__ x4 = (const float4*)x;
    float4 acc = make_float4(0.f, 0.f, 0.f, 0.f);
    for (int r = bid * 4 + rofs; r < NROWS; r += 4 * nblocks) {
        float4 v = x4[r * 64 + c4];
        acc.x += v.x; acc.y += v.y; acc.z += v.z; acc.w += v.w;
    }

    __shared__ float4 s[256];
    s[t] = acc;
    __syncthreads();
    if (t < 64) {
        float4 a = s[t], b = s[t + 64], c = s[t + 128], d = s[t + 192];
        float4 r;
        r.x = a.x + b.x + c.x + d.x;
        r.y = a.y + b.y + c.y + d.y;
        r.z = a.z + b.z + c.z + d.z;
        r.w = a.w + b.w + c.w + d.w;
        ((float4*)wsA)[bid * 64 + t] = r;
    }
}

// ---------------------------------------------------------------------------
// K2: fused tail + broadcast. TB=8 blocks x 512 threads.
//  Phase A: each block (redundantly, 128 KB each) reduces nb partials ->
//           colmean[256] in LDS. 512 threads = 64 float4-cols x 8 groups.
//  Phase B: block b owns hidden dims b*64..b*64+63; c-dim split across the
//           8 waves; LDS-combine, relu, dot with W2 chunk -> partial s_b.
//  Publish: atomicExch(ws2[b]) + fence + atomicAdd(cnt). All-atomic protocol
//           (plain loads after a flag could hit stale per-XCD L2).
//  Wait:    thread 0 polls cnt==TB, sums ws2[0..7] IN FIXED ORDER via atomic
//           loads (deterministic), relu(+b2) -> LDS broadcast.
//  Phase D: 8 blocks x 512 threads x 1 float4 = 16384 floats of out.
// Garbage-safe: cnt zeroed by K1; ws2 written before any read is permitted.
// ---------------------------------------------------------------------------
__global__ __launch_bounds__(512) void fused_tail(const float* __restrict__ wsA,
                                                  const float* __restrict__ W1,
                                                  const float* __restrict__ b1,
                                                  const float* __restrict__ W2,
                                                  const float* __restrict__ b2,
                                                  float* __restrict__ ws2,
                                                  unsigned int* __restrict__ cnt,
                                                  float* __restrict__ out,
                                                  int nb) {
    __shared__ float4 tmp4[512];
    __shared__ float  colmean[NCOLS];
    __shared__ float  part[512];
    __shared__ float  s_bcast;

    const int t = threadIdx.x;
    const int b = blockIdx.x;        // 0..7

    // ---- Phase A: colmean ----
    {
        const int c4  = t & 63;
        const int grp = t >> 6;      // 0..7
        const int per = nb >> 3;     // partials per group
        const float4* __restrict__ wsA4 = (const float4*)wsA;

        float4 acc = make_float4(0.f, 0.f, 0.f, 0.f);
        const int k0 = grp * per;
        #pragma unroll 4
        for (int k = k0; k < k0 + per; ++k) {
            float4 v = wsA4[k * 64 + c4];
            acc.x += v.x; acc.y += v.y; acc.z += v.z; acc.w += v.w;
        }
        tmp4[t] = acc;
        __syncthreads();
        if (t < 64) {
            float4 a = tmp4[t];
            #pragma unroll
            for (int g = 1; g < 8; ++g) {
                float4 v = tmp4[g * 64 + t];
                a.x += v.x; a.y += v.y; a.z += v.z; a.w += v.w;
            }
            const float inv = 1.0f / (float)NNODES;
            a.x *= inv; a.y *= inv; a.z *= inv; a.w *= inv;
            ((float4*)colmean)[t] = a;
        }
        __syncthreads();
    }

    // ---- Phase B: h chunk + partial s_b ----
    {
        const int w   = t >> 6;      // wave 0..7 -> c range
        const int l   = t & 63;      // lane -> hidden dim within chunk
        const int myt = b * 64 + l;

        float pa = 0.f;
        const int cbase = w * 32;
        #pragma unroll
        for (int c = cbase; c < cbase + 32; ++c)
            pa = fmaf(colmean[c], W1[c * HID + myt], pa);
        part[t] = pa;
        __syncthreads();

        if (t < 64) {
            float hs = b1[myt];
            #pragma unroll
            for (int g = 0; g < 8; ++g)
                hs += part[g * 64 + l];
            const float h = fmaxf(hs, 0.0f);

            float p = h * W2[myt];
            #pragma unroll
            for (int off = 32; off > 0; off >>= 1)
                p += __shfl_down(p, off, 64);
            if (l == 0) {
                atomicExch(&ws2[b], p);   // publish at coherent point
                __threadfence();
                atomicAdd(cnt, 1u);
            }
        }
    }

    // ---- Wait + deterministic combine ----
    if (t == 0) {
        while (atomicAdd(cnt, 0u) < (unsigned)TB)
            __builtin_amdgcn_s_sleep(8);
        float s = b2[0];
        #pragma unroll
        for (int i = 0; i < TB; ++i)
            s += atomicAdd(&ws2[i], 0.0f);   // atomic load (coherent)
        s_bcast = fmaxf(s, 0.0f);
    }
    __syncthreads();

    // ---- Phase D: broadcast slice (8*512 float4 = 16384 floats) ----
    const float v = s_bcast;
    ((float4*)out)[b * 512 + t] = make_float4(v, v, v, v);
}

extern "C" void kernel_launch(void* const* d_in, const int* in_sizes, int n_in,
                              void* d_out, int out_size, void* d_ws, size_t ws_size,
                              hipStream_t stream) {
    const float* x  = (const float*)d_in[0];
    const float* W1 = (const float*)d_in[1];
    const float* b1 = (const float*)d_in[2];
    const float* W2 = (const float*)d_in[3];
    const float* b2 = (const float*)d_in[4];
    float* out = (float*)d_out;
    float* ws  = (float*)d_ws;

    // nb partial-colsum blocks (multiple of 8 for the tail's 8-way split).
    int nb = 128;
    {
        size_t need = ((size_t)nb * NCOLS + TB + 1) * sizeof(float);
        if (ws_size < need) {
            nb = (int)((ws_size / sizeof(float) - (TB + 1)) / NCOLS);
            nb &= ~7;
            if (nb < 8) nb = 8;     // ws pathologically small; still correct
        }
    }
    float*        wsA = ws;                                  // nb*256 floats
    float*        ws2 = ws + (size_t)nb * NCOLS;             // 8 floats
    unsigned int* cnt = (unsigned int*)(ws2 + TB);           // 1 uint

    colsum_partial<<<nb, 256, 0, stream>>>(x, wsA, cnt, nb);
    fused_tail<<<TB, 512, 0, stream>>>(wsA, W1, b1, W2, b2, ws2, cnt, out, nb);
}

// Round 5
// 16.339 us; speedup vs baseline: 1.1366x; 1.0929x over previous
//
#include <hip/hip_runtime.h>

// Problem constants (fixed by the reference)
#define NROWS   12288   // NUM_INPUT_ROWS
#define NCOLS   256     // CODEBOOK_DIM
#define HID     512     // HIDDEN_DIM
#define NNODES  16384   // NUM_NODES (zero-padded rows contribute nothing to the sum)
#define NB      256     // partial-colsum blocks (compile-time: enables full unroll)
#define ITERS   (NROWS / (4 * NB))   // = 12 row-group iterations per thread

// ---------------------------------------------------------------------------
// K1: partial column sums of x. x is [NROWS][NCOLS] f32 row-major = 64 float4
// per row. NB=256 blocks x 256 threads (one block/CU). Thread t owns
// float4-col (t&63), row offset (t>>6). Compile-time trip count ITERS=12 ->
// fully unrolled -> 12 independent 16B loads in flight per thread.
// ---------------------------------------------------------------------------
__global__ __launch_bounds__(256) void colsum_partial_256(const float* __restrict__ x,
                                                          float* __restrict__ wsA) {
    const int t    = threadIdx.x;
    const int c4   = t & 63;
    const int rofs = t >> 6;
    const int bid  = blockIdx.x;
    const float4* __restrict__ x4 = (const float4*)x;

    float4 acc = make_float4(0.f, 0.f, 0.f, 0.f);
    #pragma unroll
    for (int k = 0; k < ITERS; ++k) {
        const int r = bid * 4 + rofs + k * (4 * NB);
        float4 v = x4[r * 64 + c4];
        acc.x += v.x; acc.y += v.y; acc.z += v.z; acc.w += v.w;
    }

    __shared__ float4 s[256];
    s[t] = acc;
    __syncthreads();
    if (t < 64) {
        float4 a = s[t], b = s[t + 64], c = s[t + 128], d = s[t + 192];
        float4 r;
        r.x = a.x + b.x + c.x + d.x;
        r.y = a.y + b.y + c.y + d.y;
        r.z = a.z + b.z + c.z + d.z;
        r.w = a.w + b.w + c.w + d.w;
        ((float4*)wsA)[bid * 64 + t] = r;
    }
}

// ---------------------------------------------------------------------------
// K2: 8 blocks x 512 threads. Block b owns hidden dims b*64 .. b*64+63.
//  Prefetch: thread t (wave w=t>>6, lane l=t&63, myt=b*64+l) loads its 32
//            W1 values W1[(w*32+j)*512 + myt] into registers FIRST -- these
//            are data-independent, so their latency overlaps Phase A.
//  Phase A:  reduce NB=256 partials -> colmean[256] in LDS. 512 threads =
//            64 float4-cols x 8 groups; 32 independent float4 loads each.
//  Phase B:  pa = sum_j colmean[w*32+j] * w1r[j]; LDS-combine across waves;
//            relu; dot with W2 chunk; wave-reduce -> partial s per block.
// ---------------------------------------------------------------------------
__global__ __launch_bounds__(512) void hidden_kernel_256(const float* __restrict__ wsA,
                                                         const float* __restrict__ W1,
                                                         const float* __restrict__ b1,
                                                         const float* __restrict__ W2,
                                                         float* __restrict__ wsB) {
    __shared__ float4 tmp4[512];
    __shared__ float  colmean[NCOLS];
    __shared__ float  part[512];

    const int t   = threadIdx.x;
    const int b   = blockIdx.x;      // 0..7
    const int w   = t >> 6;          // wave 0..7 -> c range [w*32, w*32+32)
    const int l   = t & 63;          // lane -> hidden dim within chunk
    const int myt = b * 64 + l;

    // ---- Prefetch W1 chunk (independent of Phase A data) ----
    float w1r[32];
    #pragma unroll
    for (int j = 0; j < 32; ++j)
        w1r[j] = W1[(w * 32 + j) * HID + myt];
    float b1r = 0.f, w2r = 0.f;
    if (t < 64) { b1r = b1[myt]; w2r = W2[myt]; }

    // ---- Phase A: colmean ----
    {
        const int c4  = t & 63;
        const int grp = t >> 6;      // 0..7
        const float4* __restrict__ wsA4 = (const float4*)wsA;

        float4 acc = make_float4(0.f, 0.f, 0.f, 0.f);
        #pragma unroll
        for (int j = 0; j < NB / 8; ++j) {
            float4 v = wsA4[(grp * (NB / 8) + j) * 64 + c4];
            acc.x += v.x; acc.y += v.y; acc.z += v.z; acc.w += v.w;
        }
        tmp4[t] = acc;
        __syncthreads();
        if (t < 64) {
            float4 a = tmp4[t];
            #pragma unroll
            for (int g = 1; g < 8; ++g) {
                float4 v = tmp4[g * 64 + t];
                a.x += v.x; a.y += v.y; a.z += v.z; a.w += v.w;
            }
            const float inv = 1.0f / (float)NNODES;
            a.x *= inv; a.y *= inv; a.z *= inv; a.w *= inv;
            ((float4*)colmean)[t] = a;
        }
        __syncthreads();
    }

    // ---- Phase B: h chunk + partial s ----
    float pa = 0.f;
    #pragma unroll
    for (int j = 0; j < 32; ++j)
        pa = fmaf(colmean[w * 32 + j], w1r[j], pa);
    part[t] = pa;
    __syncthreads();

    if (t < 64) {
        float hs = b1r;
        #pragma unroll
        for (int g = 0; g < 8; ++g)
            hs += part[g * 64 + l];
        const float h = fmaxf(hs, 0.0f);

        float p = h * w2r;
        #pragma unroll
        for (int off = 32; off > 0; off >>= 1)
            p += __shfl_down(p, off, 64);
        if (l == 0) wsB[b] = p;
    }
}

// ---------------------------------------------------------------------------
// K3: 16 blocks x 256 threads. Sum 8 partial s, relu(+b2), broadcast.
// ---------------------------------------------------------------------------
__global__ __launch_bounds__(256) void broadcast_kernel(const float* __restrict__ wsB,
                                                        const float* __restrict__ b2,
                                                        float* __restrict__ out) {
    __shared__ float sval;
    if (threadIdx.x == 0) {
        float s = b2[0];
        #pragma unroll
        for (int i = 0; i < 8; ++i) s += wsB[i];
        sval = fmaxf(s, 0.0f);
    }
    __syncthreads();
    const float v = sval;
    ((float4*)out)[blockIdx.x * 256 + threadIdx.x] = make_float4(v, v, v, v);
}

// ---------------- Fallback (only if ws_size < 256KB+32B; not expected) ------
__global__ __launch_bounds__(256) void colsum_partial_dyn(const float* __restrict__ x,
                                                          float* __restrict__ wsA,
                                                          int nblocks) {
    const int t = threadIdx.x, c4 = t & 63, rofs = t >> 6, bid = blockIdx.x;
    const float4* __restrict__ x4 = (const float4*)x;
    float4 acc = make_float4(0.f, 0.f, 0.f, 0.f);
    for (int r = bid * 4 + rofs; r < NROWS; r += 4 * nblocks) {
        float4 v = x4[r * 64 + c4];
        acc.x += v.x; acc.y += v.y; acc.z += v.z; acc.w += v.w;
    }
    __shared__ float4 s[256];
    s[t] = acc;
    __syncthreads();
    if (t < 64) {
        float4 a = s[t], b = s[t + 64], c = s[t + 128], d = s[t + 192];
        float4 r; r.x=a.x+b.x+c.x+d.x; r.y=a.y+b.y+c.y+d.y; r.z=a.z+b.z+c.z+d.z; r.w=a.w+b.w+c.w+d.w;
        ((float4*)wsA)[bid * 64 + t] = r;
    }
}
__global__ __launch_bounds__(512) void hidden_kernel_dyn(const float* __restrict__ wsA,
                                                         const float* __restrict__ W1,
                                                         const float* __restrict__ b1,
                                                         const float* __restrict__ W2,
                                                         float* __restrict__ wsB,
                                                         int nb) {
    __shared__ float4 tmp4[512];
    __shared__ float  colmean[NCOLS];
    __shared__ float  part[512];
    const int t = threadIdx.x, b = blockIdx.x;
    {
        const int c4 = t & 63, grp = t >> 6, per = nb >> 3;
        const float4* __restrict__ wsA4 = (const float4*)wsA;
        float4 acc = make_float4(0.f, 0.f, 0.f, 0.f);
        for (int k = grp * per; k < grp * per + per; ++k) {
            float4 v = wsA4[k * 64 + c4];
            acc.x += v.x; acc.y += v.y; acc.z += v.z; acc.w += v.w;
        }
        tmp4[t] = acc;
        __syncthreads();
        if (t < 64) {
            float4 a = tmp4[t];
            for (int g = 1; g < 8; ++g) {
                float4 v = tmp4[g * 64 + t];
                a.x += v.x; a.y += v.y; a.z += v.z; a.w += v.w;
            }
            const float inv = 1.0f / (float)NNODES;
            a.x *= inv; a.y *= inv; a.z *= inv; a.w *= inv;
            ((float4*)colmean)[t] = a;
        }
        __syncthreads();
    }
    const int w = t >> 6, l = t & 63, myt = b * 64 + l;
    float pa = 0.f;
    for (int c = w * 32; c < w * 32 + 32; ++c)
        pa = fmaf(colmean[c], W1[c * HID + myt], pa);
    part[t] = pa;
    __syncthreads();
    if (t < 64) {
        float hs = b1[myt];
        for (int g = 0; g < 8; ++g) hs += part[g * 64 + l];
        const float h = fmaxf(hs, 0.0f);
        float p = h * W2[myt];
        for (int off = 32; off > 0; off >>= 1) p += __shfl_down(p, off, 64);
        if (l == 0) wsB[b] = p;
    }
}

extern "C" void kernel_launch(void* const* d_in, const int* in_sizes, int n_in,
                              void* d_out, int out_size, void* d_ws, size_t ws_size,
                              hipStream_t stream) {
    const float* x  = (const float*)d_in[0];
    const float* W1 = (const float*)d_in[1];
    const float* b1 = (const float*)d_in[2];
    const float* W2 = (const float*)d_in[3];
    const float* b2 = (const float*)d_in[4];
    float* out = (float*)d_out;
    float* ws  = (float*)d_ws;

    if (ws_size >= (size_t)(NB * NCOLS + 8) * sizeof(float)) {
        float* wsA = ws;
        float* wsB = ws + (size_t)NB * NCOLS;
        colsum_partial_256<<<NB, 256, 0, stream>>>(x, wsA);
        hidden_kernel_256<<<8, 512, 0, stream>>>(wsA, W1, b1, W2, wsB);
        broadcast_kernel<<<16, 256, 0, stream>>>(wsB, b2, out);
    } else {
        int nb = (int)((ws_size / sizeof(float) - 8) / NCOLS);
        nb &= ~7; if (nb < 8) nb = 8;
        float* wsA = ws;
        float* wsB = ws + (size_t)nb * NCOLS;
        colsum_partial_dyn<<<nb, 256, 0, stream>>>(x, wsA, nb);
        hidden_kernel_dyn<<<8, 512, 0, stream>>>(wsA, W1, b1, W2, wsB, nb);
        broadcast_kernel<<<16, 256, 0, stream>>>(wsB, b2, out);
    }
}